// Round 3
// baseline (572.855 us; speedup 1.0000x reference)
//
#include <hip/hip_runtime.h>

// ---------------------------------------------------------------------------
// MoE FFN: SEQ=8192, IN_DIM=1024, HID=2048, 8 experts, topk=2, gelu(tanh) gate
// R6: (1) gemm1 work order: XCD owns n-col pair, n-fastest within tile ->
// X-tile re-read becomes same-XCD L2 hit (was LLC/HBM; FETCH=2.5x compulsory).
// (2) gemm2 rewritten to M=128 tiles (~528 blocks vs 272 -> kills the ~85us
// second-round tail), 2-phase/K-tile pipeline with re-derived vmcnt ledger.
// (3) three cast launches fused into one. gemm1 inner loop unchanged (control).
// ---------------------------------------------------------------------------

#define SEQ 8192
#define IN_DIM 1024
#define HID 2048
#define NEXP 8
#define TOPK 2
#define NSLOT (SEQ * TOPK)

#define BM 128            // legacy (route_kernel tile table, unused by gemms)
#define BK 64
#define BM1 256
#define MAX_T1 72
#define MAX_T2 140        // max m-tiles at M=128 (128 + 8 partials, padded)

typedef unsigned short ushort_t;
typedef __bf16 bf16x8 __attribute__((ext_vector_type(8)));
typedef float f32x4 __attribute__((ext_vector_type(4)));

__device__ __forceinline__ ushort_t f2bf(float f) {
    union { float f; unsigned u; } v;
    v.f = f;
    unsigned r = v.u + 0x7FFFu + ((v.u >> 16) & 1u);
    return (ushort_t)(r >> 16);
}

__device__ __forceinline__ float gelu_tanh(float x) {
    float u = 0.7978845608028654f * x * (1.0f + 0.044715f * x * x);
    return x / (1.0f + __expf(-2.0f * u));
}

__device__ __forceinline__ void async16(const void* g, void* l) {
    __builtin_amdgcn_global_load_lds(
        (const __attribute__((address_space(1))) unsigned int*)g,
        (__attribute__((address_space(3))) unsigned int*)l, 16, 0, 0);
}

// ---------------------------------------------------------------------------
// fused cast: inp (8.39M) + up (16.78M) + gate (16.78M) fp32 -> bf16
__global__ void cast3_kernel(const float* __restrict__ inp,
                             const float* __restrict__ up,
                             const float* __restrict__ gate,
                             ushort_t* __restrict__ o_inp,
                             ushort_t* __restrict__ o_up,
                             ushort_t* __restrict__ o_gate) {
    const int N1 = SEQ * IN_DIM;
    const int N2 = NEXP * HID * IN_DIM;
    long i = (long)(blockIdx.x * blockDim.x + threadIdx.x) * 4;
    const float* src;
    ushort_t* dst;
    if (i < N1)            { src = inp  + i;            dst = o_inp  + i; }
    else if (i < N1 + N2)  { src = up   + (i - N1);     dst = o_up   + (i - N1); }
    else                   { src = gate + (i - N1 - N2); dst = o_gate + (i - N1 - N2); }
    float4 v = *(const float4*)src;
    union { ushort_t u[4]; uint2 v; } o;
    o.u[0] = f2bf(v.x); o.u[1] = f2bf(v.y);
    o.u[2] = f2bf(v.z); o.u[3] = f2bf(v.w);
    *(uint2*)dst = o.v;
}

// down_proj [8][2048][1024] fp32 -> [8][1024][2048] bf16
__global__ void transpose_cast_kernel(const float* __restrict__ in,
                                      ushort_t* __restrict__ out) {
    __shared__ float tile[32][33];
    int e = blockIdx.z;
    int d0 = blockIdx.x * 32, h0 = blockIdx.y * 32;
    int tx = threadIdx.x & 31, ty = threadIdx.x >> 5;
    const float* src = in + (size_t)e * HID * IN_DIM;
    for (int j = 0; j < 32; j += 8)
        tile[ty + j][tx] = src[(size_t)(h0 + ty + j) * IN_DIM + d0 + tx];
    __syncthreads();
    ushort_t* dst = out + (size_t)e * IN_DIM * HID;
    for (int j = 0; j < 32; j += 8)
        dst[(size_t)(d0 + ty + j) * HID + h0 + tx] = f2bf(tile[tx][ty + j]);
}

// ---------------------------------------------------------------------------
__global__ void route_kernel(const int* __restrict__ sel,
                             const float* __restrict__ wts,
                             int* __restrict__ meta,
                             int* __restrict__ stok,
                             int* __restrict__ sinv) {
    __shared__ int lc[256][NEXP];
    __shared__ int tot[NEXP];
    __shared__ int s_off[NEXP + 1];
    int t = threadIdx.x;
    int cnt[NEXP];
#pragma unroll
    for (int e = 0; e < NEXP; e++) cnt[e] = 0;
    int base = t * (NSLOT / 256);
    for (int i = 0; i < NSLOT / 256; i++) cnt[sel[base + i]]++;
#pragma unroll
    for (int e = 0; e < NEXP; e++) lc[t][e] = cnt[e];
    __syncthreads();
    if (t < NEXP) {
        int run = 0;
        for (int i = 0; i < 256; i++) { int v = lc[i][t]; lc[i][t] = run; run += v; }
        tot[t] = run;
    }
    __syncthreads();
    if (t == 0) {
        int o = 0;
        for (int e = 0; e < NEXP; e++) { s_off[e] = o; o += tot[e]; }
        s_off[NEXP] = o;
        for (int e = 0; e <= NEXP; e++) meta[e] = s_off[e];
        int nt = 0;
        for (int e = 0; e < NEXP; e++) {
            int c = s_off[e + 1] - s_off[e];
            int m = (c + BM - 1) / BM;
            for (int i = 0; i < m; i++) { meta[32 + 2 * nt] = e; meta[33 + 2 * nt] = i; nt++; }
        }
        meta[16] = nt;
    }
    __syncthreads();
    int cur[NEXP];
#pragma unroll
    for (int e = 0; e < NEXP; e++) cur[e] = s_off[e] + lc[t][e];
    for (int i = 0; i < NSLOT / 256; i++) {
        int slot = base + i;
        int e = sel[slot];
        int pos = cur[e]++;
        stok[pos] = slot >> 1;
        sinv[slot] = pos;
    }
}

// ---------------------------------------------------------------------------
// Shared macros (BK=64, 128-row streams, 8 waves).
// ---------------------------------------------------------------------------
#define ST_A(b, h, koff) {                                                 \
        async16(pA[h][0] + (koff), &AT[b][h][(w * 16) * BK]);              \
        async16(pA[h][1] + (koff), &AT[b][h][(w * 16 + 8) * BK]); }
#define ST_U(b, koff) {                                                    \
        async16(pU[0] + (koff), &UT[b][(w * 16) * BK]);                    \
        async16(pU[1] + (koff), &UT[b][(w * 16 + 8) * BK]); }
#define ST_G(b, koff) {                                                    \
        async16(pG[0] + (koff), &GT[b][(w * 16) * BK]);                    \
        async16(pG[1] + (koff), &GT[b][(w * 16 + 8) * BK]); }

#define RD_A(b, mb) {                                                      \
        _Pragma("unroll") for (int mi = 0; mi < 4; mi++)                   \
        _Pragma("unroll") for (int kh = 0; kh < 2; kh++)                   \
            a[mi][kh] = *(const bf16x8*)&AT[b][wm][                        \
                ((mb) + mi * 16 + r4) * BK + (((kh * 4 + q) ^ sw7) << 3)]; }
#define RD_U(b) {                                                          \
        _Pragma("unroll") for (int ni = 0; ni < 2; ni++)                   \
        _Pragma("unroll") for (int kh = 0; kh < 2; kh++)                   \
            bu[ni][kh] = *(const bf16x8*)&UT[b][                           \
                (wn * 32 + ni * 16 + r4) * BK + (((kh * 4 + q) ^ sw7) << 3)]; }
#define RD_G(b) {                                                          \
        _Pragma("unroll") for (int ni = 0; ni < 2; ni++)                   \
        _Pragma("unroll") for (int kh = 0; kh < 2; kh++)                   \
            bg[ni][kh] = *(const bf16x8*)&GT[b][                           \
                (wn * 32 + ni * 16 + r4) * BK + (((kh * 4 + q) ^ sw7) << 3)]; }

#define MM(ACC, mb2, BB) {                                                 \
        _Pragma("unroll") for (int mi = 0; mi < 4; mi++)                   \
        _Pragma("unroll") for (int ni = 0; ni < 2; ni++)                   \
        _Pragma("unroll") for (int kh = 0; kh < 2; kh++)                   \
            ACC[(mb2) + mi][ni] = __builtin_amdgcn_mfma_f32_16x16x32_bf16( \
                a[mi][kh], BB[ni][kh], ACC[(mb2) + mi][ni], 0, 0, 0); }

#define BARRIER __builtin_amdgcn_s_barrier()
#define LGKM0 asm volatile("s_waitcnt lgkmcnt(0)" ::: "memory")
#define VMW4 asm volatile("s_waitcnt vmcnt(4)" ::: "memory")
#define VMW2 asm volatile("s_waitcnt vmcnt(2)" ::: "memory")
#define VMW0 asm volatile("s_waitcnt vmcnt(0)" ::: "memory")
#define PRIO1 __builtin_amdgcn_s_setprio(1)
#define PRIO0 __builtin_amdgcn_s_setprio(0)

// ---- gemm1 8-phase body (2 K-tiles), unchanged from R5 -------------------
#define KPRO                                                               \
    ST_A(0, 0, 0); ST_A(0, 1, 0); ST_U(0, 0); ST_G(0, 0);                  \
    ST_A(1, 0, 64);                                                        \
    VMW2; BARRIER;

#define KBODY_FULL                                                         \
    RD_A(0, 0); RD_U(0); ST_A(1, 1, 64); BARRIER; LGKM0;                   \
    PRIO1; MM(accH, 0, bu); PRIO0; BARRIER;                                \
    RD_G(0); ST_U(1, 64); BARRIER; LGKM0;                                  \
    PRIO1; MM(accG, 0, bg); PRIO0; BARRIER;                                \
    RD_A(0, 64); ST_G(1, 64); BARRIER; LGKM0;                              \
    PRIO1; MM(accG, 4, bg); PRIO0; BARRIER;                                \
    ST_A(0, 0, 128); VMW2; BARRIER;                                        \
    PRIO1; MM(accH, 4, bu); PRIO0; BARRIER;                                \
    RD_A(1, 0); RD_U(1); ST_A(0, 1, 128); BARRIER; LGKM0;                  \
    PRIO1; MM(accH, 0, bu); PRIO0; BARRIER;                                \
    RD_G(1); ST_U(0, 128); BARRIER; LGKM0;                                 \
    PRIO1; MM(accG, 0, bg); PRIO0; BARRIER;                                \
    RD_A(1, 64); ST_G(0, 128); BARRIER; LGKM0;                             \
    PRIO1; MM(accG, 4, bg); PRIO0; BARRIER;                                \
    ST_A(1, 0, 192); VMW2; BARRIER;                                        \
    PRIO1; MM(accH, 4, bu); PRIO0; BARRIER;

#define KBODY_ADV {                                                        \
    pA[0][0] += 128; pA[0][1] += 128; pA[1][0] += 128; pA[1][1] += 128;    \
    pU[0] += 128; pU[1] += 128; pG[0] += 128; pG[1] += 128; }

#define KBODY_TAIL                                                         \
    RD_A(0, 0); RD_U(0); ST_A(1, 1, 64); BARRIER; LGKM0;                   \
    PRIO1; MM(accH, 0, bu); PRIO0; BARRIER;                                \
    RD_G(0); ST_U(1, 64); BARRIER; LGKM0;                                  \
    PRIO1; MM(accG, 0, bg); PRIO0; BARRIER;                                \
    RD_A(0, 64); ST_G(1, 64); BARRIER; LGKM0;                              \
    PRIO1; MM(accG, 4, bg); PRIO0; BARRIER;                                \
    VMW0; BARRIER;                                                         \
    PRIO1; MM(accH, 4, bu); PRIO0; BARRIER;                                \
    RD_A(1, 0); RD_U(1); BARRIER; LGKM0;                                   \
    PRIO1; MM(accH, 0, bu); PRIO0; BARRIER;                                \
    RD_G(1); BARRIER; LGKM0;                                               \
    PRIO1; MM(accG, 0, bg); PRIO0; BARRIER;                                \
    RD_A(1, 64); BARRIER; LGKM0;                                           \
    PRIO1; MM(accG, 4, bg); PRIO0; BARRIER;                                \
    PRIO1; MM(accH, 4, bu); PRIO0;

// ---------------------------------------------------------------------------
// GEMM1: act = gelu(x@Wg^T) * (x@Wu^T). Tile 256 x (128 U-cols + 128 G-cols).
// Work order: XCD k owns n-cols {2k,2k+1}; within XCD, n varies fastest per
// tile (tile = j>>1, ncol = 2k + (j&1)) -> X-tile re-read is same-XCD L2 hit.
__global__ __launch_bounds__(512, 2) void gemm1_kernel(
    const ushort_t* __restrict__ X,
    const ushort_t* __restrict__ U,
    const ushort_t* __restrict__ G,
    const int* __restrict__ meta,
    const int* __restrict__ stok,
    ushort_t* __restrict__ act) {
    __shared__ __align__(16) ushort_t AT[2][2][128 * BK];   // 64 KB
    __shared__ __align__(16) ushort_t UT[2][128 * BK];      // 32 KB
    __shared__ __align__(16) ushort_t GT[2][128 * BK];      // 32 KB
    __shared__ int s_tok[BM1];

    int id = blockIdx.x + MAX_T1 * blockIdx.y;   // 0..1151
    int xcd = id & 7;
    int j = id >> 3;                             // 0..143
    int tile = j >> 1;                           // 0..71
    int n0 = ((xcd << 1) | (j & 1)) * 128;       // XCD owns col pair

    // derive (expert, m-tile) from per-expert offsets
    int e = -1, mt = 0, accT = 0;
#pragma unroll
    for (int ee = 0; ee < NEXP; ee++) {
        int c = meta[ee + 1] - meta[ee];
        int m = (c + BM1 - 1) >> 8;
        if (tile >= accT && tile < accT + m) { e = ee; mt = tile - accT; }
        accT += m;
    }
    if (e < 0) return;
    int off = meta[e];
    int cnt = meta[e + 1] - off;
    int m0 = mt * BM1;

    int tid = threadIdx.x;
    if (tid < BM1) {
        int r = m0 + tid;
        if (r >= cnt) r = cnt - 1;
        s_tok[tid] = stok[off + r];
    }
    __syncthreads();

    int lane = tid & 63;
    int w = tid >> 6;        // 0..7
    int wm = w >> 2;         // 0..1  (row half)
    int wn = w & 3;          // 0..3  (32-col group)
    int srow = lane >> 3;
    int schunk = lane & 7;
    int gchunk = schunk ^ srow;     // pre-swizzled source chunk
    int r4 = lane & 15;
    int q = lane >> 4;
    int sw7 = r4 & 7;

    const ushort_t* pA[2][2];
#pragma unroll
    for (int h = 0; h < 2; h++)
#pragma unroll
        for (int jj = 0; jj < 2; jj++) {
            int r = h * 128 + w * 16 + jj * 8 + srow;
            pA[h][jj] = X + (size_t)s_tok[r] * IN_DIM + gchunk * 8;
        }
    const ushort_t* Ue = U + ((size_t)e * HID + n0) * IN_DIM;
    const ushort_t* Ge = G + ((size_t)e * HID + n0) * IN_DIM;
    const ushort_t* pU[2];
    const ushort_t* pG[2];
#pragma unroll
    for (int jj = 0; jj < 2; jj++) {
        int r = w * 16 + jj * 8 + srow;
        pU[jj] = Ue + (size_t)r * IN_DIM + gchunk * 8;
        pG[jj] = Ge + (size_t)r * IN_DIM + gchunk * 8;
    }

    f32x4 accH[8][2], accG[8][2];
#pragma unroll
    for (int mi = 0; mi < 8; mi++)
#pragma unroll
        for (int ni = 0; ni < 2; ni++) {
            accH[mi][ni] = (f32x4){0.f, 0.f, 0.f, 0.f};
            accG[mi][ni] = (f32x4){0.f, 0.f, 0.f, 0.f};
        }

    bf16x8 a[4][2], bu[2][2], bg[2][2];

    KPRO;
#pragma unroll 1
    for (int i = 0; i < (IN_DIM / BK) / 2 - 1; ++i) {   // 7 bodies
        KBODY_FULL;
        KBODY_ADV;
    }
    KBODY_TAIL;

#pragma unroll
    for (int mf = 0; mf < 8; mf++) {
#pragma unroll
        for (int r = 0; r < 4; r++) {
            int row_local = wm * 128 + mf * 16 + q * 4 + r;
            int grow = m0 + row_local;
            if (grow >= cnt) continue;
            size_t orow = (size_t)(off + grow) * HID + n0 + wn * 32;
#pragma unroll
            for (int ni = 0; ni < 2; ni++) {
                float h = accH[mf][ni][r];
                float g = accG[mf][ni][r];
                act[orow + ni * 16 + r4] = f2bf(gelu_tanh(g) * h);
            }
        }
    }
}

// ---------------------------------------------------------------------------
// GEMM2: y[pos] = act[pos] @ Wd. M=128 tiles, N=256 (two 128-col streams),
// BK=64, K=2048 (32 K-tiles). 2 phases/K-tile, 16 MFMA each, 8 waves
// (2 row-halves x 4 col-groups), per-wave 64x32 of each stream.
// vmcnt ledger: invariant at ph1(t,b): [b].A,U landed, [b].G 2-outstanding.
//   ph1: RD A,U(b); ST A,U(b^1); bar; lgkm0; MM(U); vmcnt(4); bar
//        (outstanding 2+4 -> leaves 4 = just-issued => [b].G landed)
//   ph2: RD G(b); ST G(b^1); bar; lgkm0; MM(G); vmcnt(2); bar
//        (outstanding 4+2 -> leaves 2 = [b^1].G => [b^1].A,U landed ✓)
// Overwrite safety: ST X(b^1) in phase p(t) targets data last read in
// phase p(t-1), whose reads completed (lgkm0) before that phase's 2nd barrier.
__global__ __launch_bounds__(512, 2) void gemm2_kernel(
    const ushort_t* __restrict__ act,
    const ushort_t* __restrict__ DT,
    const int* __restrict__ meta,
    float* __restrict__ y) {            // [NSLOT][IN_DIM] fp32
    __shared__ __align__(16) ushort_t AT2[2][128 * BK];   // 32 KB
    __shared__ __align__(16) ushort_t UT2[2][128 * BK];   // 32 KB
    __shared__ __align__(16) ushort_t GT2[2][128 * BK];   // 32 KB

    // XCD-chunked, n-fastest-within-tile: 560 = 8 * 70
    int id = blockIdx.x + MAX_T2 * blockIdx.y;   // 0..559
    int xcd = id & 7;
    int jj0 = id >> 3;                           // 0..69
    int wk = xcd * 70 + jj0;
    int tile = wk >> 2;                          // 0..139
    int n0 = (wk & 3) * 256;

    // derive (expert, m-tile) at M=128
    int e = -1, mt = 0, accT = 0;
#pragma unroll
    for (int ee = 0; ee < NEXP; ee++) {
        int c = meta[ee + 1] - meta[ee];
        int m = (c + 127) >> 7;
        if (tile >= accT && tile < accT + m) { e = ee; mt = tile - accT; }
        accT += m;
    }
    if (e < 0) return;
    int off = meta[e];
    int cnt = meta[e + 1] - off;
    int m0 = mt * 128;

    int tid = threadIdx.x;
    int lane = tid & 63;
    int w = tid >> 6;
    int wm = w >> 2;         // 0..1 (32-row half of the 128? no: 64-row half)
    int wn = w & 3;          // 0..3 (32-col group in each stream)
    int srow = lane >> 3;
    int schunk = lane & 7;
    int gchunk = schunk ^ srow;
    int r4 = lane & 15;
    int q = lane >> 4;
    int sw7 = r4 & 7;

    const ushort_t* Ae = act + (size_t)off * HID;
    const ushort_t* pA2[2];
#pragma unroll
    for (int jj = 0; jj < 2; jj++) {
        int ar = m0 + w * 16 + jj * 8 + srow;
        if (ar >= cnt) ar = cnt - 1;
        pA2[jj] = Ae + (size_t)ar * HID + gchunk * 8;
    }
    const ushort_t* Be = DT + ((size_t)e * IN_DIM + n0) * HID;
    const ushort_t* pU2[2];
    const ushort_t* pG2[2];
#pragma unroll
    for (int jj = 0; jj < 2; jj++) {
        int r = w * 16 + jj * 8 + srow;
        pU2[jj] = Be + (size_t)r * HID + gchunk * 8;
        pG2[jj] = Be + (size_t)(128 + r) * HID + gchunk * 8;
    }

    f32x4 accU[4][2], accGG[4][2];
#pragma unroll
    for (int mi = 0; mi < 4; mi++)
#pragma unroll
        for (int ni = 0; ni < 2; ni++) {
            accU[mi][ni] = (f32x4){0.f, 0.f, 0.f, 0.f};
            accGG[mi][ni] = (f32x4){0.f, 0.f, 0.f, 0.f};
        }

    bf16x8 a[4][2], bu[2][2], bg[2][2];

#define ST_A2(b, koff) {                                                   \
        async16(pA2[0] + (koff), &AT2[b][(w * 16) * BK]);                  \
        async16(pA2[1] + (koff), &AT2[b][(w * 16 + 8) * BK]); }
#define ST_U2(b, koff) {                                                   \
        async16(pU2[0] + (koff), &UT2[b][(w * 16) * BK]);                  \
        async16(pU2[1] + (koff), &UT2[b][(w * 16 + 8) * BK]); }
#define ST_G2(b, koff) {                                                   \
        async16(pG2[0] + (koff), &GT2[b][(w * 16) * BK]);                  \
        async16(pG2[1] + (koff), &GT2[b][(w * 16 + 8) * BK]); }
#define RD_A2(b) {                                                         \
        _Pragma("unroll") for (int mi = 0; mi < 4; mi++)                   \
        _Pragma("unroll") for (int kh = 0; kh < 2; kh++)                   \
            a[mi][kh] = *(const bf16x8*)&AT2[b][                           \
                (wm * 64 + mi * 16 + r4) * BK + (((kh * 4 + q) ^ sw7) << 3)]; }
#define RD_U2(b) {                                                         \
        _Pragma("unroll") for (int ni = 0; ni < 2; ni++)                   \
        _Pragma("unroll") for (int kh = 0; kh < 2; kh++)                   \
            bu[ni][kh] = *(const bf16x8*)&UT2[b][                          \
                (wn * 32 + ni * 16 + r4) * BK + (((kh * 4 + q) ^ sw7) << 3)]; }
#define RD_G2(b) {                                                         \
        _Pragma("unroll") for (int ni = 0; ni < 2; ni++)                   \
        _Pragma("unroll") for (int kh = 0; kh < 2; kh++)                   \
            bg[ni][kh] = *(const bf16x8*)&GT2[b][                          \
                (wn * 32 + ni * 16 + r4) * BK + (((kh * 4 + q) ^ sw7) << 3)]; }

#define G2BODY(b)                                                          \
    RD_A2(b); RD_U2(b); ST_A2(b ^ 1, 64); ST_U2(b ^ 1, 64); BARRIER; LGKM0;\
    PRIO1; MM(accU, 0, bu); PRIO0; VMW4; BARRIER;                          \
    RD_G2(b); ST_G2(b ^ 1, 64); BARRIER; LGKM0;                            \
    PRIO1; MM(accGG, 0, bg); PRIO0; VMW2; BARRIER;

#define G2TAIL(b)                                                          \
    RD_A2(b); RD_U2(b); BARRIER; LGKM0;                                    \
    PRIO1; MM(accU, 0, bu); PRIO0; VMW0; BARRIER;                          \
    RD_G2(b); BARRIER; LGKM0;                                              \
    PRIO1; MM(accGG, 0, bg); PRIO0;

#define G2ADV {                                                            \
    pA2[0] += 64; pA2[1] += 64; pU2[0] += 64; pU2[1] += 64;                \
    pG2[0] += 64; pG2[1] += 64; }

    // prologue: tile0 A,U,G (6 loads); invariant: A,U landed, G outstanding 2
    ST_A2(0, 0); ST_U2(0, 0); ST_G2(0, 0);
    VMW2; BARRIER;

    // 32 K-tiles: 31 full bodies (15 pairs + 1) + tail
#pragma unroll 1
    for (int i = 0; i < 15; i++) {
        G2BODY(0); G2ADV;
        G2BODY(1); G2ADV;
    }
    G2BODY(0); G2ADV;
    G2TAIL(1);

#pragma unroll
    for (int mi = 0; mi < 4; mi++) {
#pragma unroll
        for (int r = 0; r < 4; r++) {
            int row_local = wm * 64 + mi * 16 + q * 4 + r;
            int grow = m0 + row_local;
            if (grow >= cnt) continue;
            float* orow = y + (size_t)(off + grow) * IN_DIM + n0 + wn * 32;
#pragma unroll
            for (int ni = 0; ni < 2; ni++) {
                orow[ni * 16 + r4] = accU[mi][ni][r];
                orow[128 + ni * 16 + r4] = accGG[mi][ni][r];
            }
        }
    }
}

// ---------------------------------------------------------------------------
// combine: out[tok] = w0*y[sinv[2tok]] + w1*y[sinv[2tok+1]]. One block/token.
__global__ __launch_bounds__(256) void combine_kernel(
    const float* __restrict__ y,
    const float* __restrict__ wts,
    const int* __restrict__ sinv,
    float* __restrict__ out) {
    int tok = blockIdx.x;
    int c = threadIdx.x;              // 256 threads x float4 = 1024 floats
    int p0 = sinv[tok * 2], p1 = sinv[tok * 2 + 1];
    float w0 = wts[tok * 2], w1 = wts[tok * 2 + 1];
    float4 a = *(const float4*)(y + (size_t)p0 * IN_DIM + c * 4);
    float4 b = *(const float4*)(y + (size_t)p1 * IN_DIM + c * 4);
    float4 o;
    o.x = w0 * a.x + w1 * b.x;
    o.y = w0 * a.y + w1 * b.y;
    o.z = w0 * a.z + w1 * b.z;
    o.w = w0 * a.w + w1 * b.w;
    *(float4*)(out + (size_t)tok * IN_DIM + c * 4) = o;
}

// ---------------------------------------------------------------------------
extern "C" void kernel_launch(void* const* d_in, const int* in_sizes, int n_in,
                              void* d_out, int out_size, void* d_ws, size_t ws_size,
                              hipStream_t stream) {
    const float* inp  = (const float*)d_in[0];
    const float* wts  = (const float*)d_in[1];
    const float* up   = (const float*)d_in[2];
    const float* gate = (const float*)d_in[3];
    const float* down = (const float*)d_in[4];
    const int*   sel  = (const int*)d_in[5];
    float* out = (float*)d_out;

    // workspace layout: y (fp32, 64 MB) ALIASES inp_bf/up_bf/part of gate_bf —
    // safe because gemm2 (writes y) is stream-ordered after gemm1 (last reader
    // of inp/up/gate_bf), and casts rewrite them every call.
    char* ws = (char*)d_ws;
    ushort_t* inp_bf  = (ushort_t*)(ws);
    ushort_t* up_bf   = (ushort_t*)(ws + 16777216);
    ushort_t* gate_bf = (ushort_t*)(ws + 50331648);
    ushort_t* down_bf = (ushort_t*)(ws + 83886080);
    ushort_t* act     = (ushort_t*)(ws + 117440512);
    int*      stok    = (int*)(ws + 184549376);
    int*      sinv    = (int*)(ws + 184614912);
    int*      meta    = (int*)(ws + 184680448);
    float*    y       = (float*)(ws);            // 64 MB, aliases bf16 inputs

    const int CAST_N = SEQ * IN_DIM + 2 * NEXP * HID * IN_DIM;   // 41.94M
    cast3_kernel<<<CAST_N / 1024, 256, 0, stream>>>(inp, up, gate,
                                                    inp_bf, up_bf, gate_bf);
    transpose_cast_kernel<<<dim3(IN_DIM / 32, HID / 32, NEXP), 256, 0, stream>>>(down, down_bf);
    route_kernel<<<1, 256, 0, stream>>>(sel, wts, meta, stok, sinv);
    gemm1_kernel<<<dim3(MAX_T1, HID / 128), 512, 0, stream>>>(inp_bf, up_bf, gate_bf, meta, stok, act);
    gemm2_kernel<<<dim3(MAX_T2, 4), 512, 0, stream>>>(act, down_bf, meta, y);
    combine_kernel<<<SEQ, 256, 0, stream>>>(y, wts, sinv, out);
}